// Round 1
// baseline (561.168 us; speedup 1.0000x reference)
//
#include <hip/hip_runtime.h>
#include <stdint.h>

// ---------- types ----------
typedef __bf16 bf16x8 __attribute__((ext_vector_type(8)));
typedef float  f32x4  __attribute__((ext_vector_type(4)));

union U16x8 { uint4 u; uint16_t s[8]; };

__device__ __forceinline__ uint16_t f2b(float f) {
    union { float f; uint32_t u; } c; c.f = f;
    uint32_t u = c.u;
    uint32_t r = u + 0x7fffu + ((u >> 16) & 1u);   // round-to-nearest-even
    return (uint16_t)(r >> 16);
}

// ---------- prep kernels ----------
// fp32 -> bf16 elementwise (vectorized float4 -> 4x bf16)
__global__ void cast_f32_bf16(const float* __restrict__ x, uint16_t* __restrict__ y, int n4) {
    int i = blockIdx.x * blockDim.x + threadIdx.x;
    if (i < n4) {
        float4 v = ((const float4*)x)[i];
        ushort4 o;
        o.x = f2b(v.x); o.y = f2b(v.y); o.z = f2b(v.z); o.w = f2b(v.w);
        *(ushort4*)(y + (size_t)i * 4) = o;
    }
}

// W [1024,1024] fp32 row-major [k][n]  ->  Wt bf16 [n][k]
__global__ void transpose_cast(const float* __restrict__ W, uint16_t* __restrict__ Wt) {
    __shared__ float tile[64][65];
    const int k0 = blockIdx.y * 64, n0 = blockIdx.x * 64;
    const int tx = threadIdx.x & 63, ty = threadIdx.x >> 6;
    #pragma unroll
    for (int r = ty; r < 64; r += 4)
        tile[r][tx] = W[(size_t)(k0 + r) * 1024 + n0 + tx];
    __syncthreads();
    #pragma unroll
    for (int r = ty; r < 64; r += 4)
        Wt[(size_t)(n0 + r) * 1024 + k0 + tx] = f2b(tile[tx][r]);
}

// ---------- GEMM: C[M=8192,N=1024] = A[M,K=1024](bf16) * Bt[N,K](bf16) + bias ----------
// MODE 0: out bf16, head-split layout [B,H,S,dk], val=(acc+bias)*scale
// MODE 1: out fp32 [M,N] row-major,               val=(acc+bias)*scale
template <int MODE>
__global__ __launch_bounds__(256, 2)
void gemm_bt(const uint16_t* __restrict__ A, const uint16_t* __restrict__ Bt,
             const float* __restrict__ bias, void* __restrict__ Cout, float scale) {
    constexpr int LDA = 40;  // LDS row stride in elements (80B: 16B-aligned, conflict-light)
    __shared__ uint16_t As[128 * LDA] __attribute__((aligned(16)));
    __shared__ uint16_t Bs[128 * LDA] __attribute__((aligned(16)));

    const int tid = threadIdx.x;
    const int m0 = blockIdx.y * 128, n0 = blockIdx.x * 128;
    const int l = tid & 63, ln = l & 15, qd = l >> 4;
    const int w = tid >> 6;
    const int wm = (w >> 1) * 64, wn = (w & 1) * 64;

    f32x4 acc[4][4] = {};

    for (int kk = 0; kk < 1024; kk += 32) {
        __syncthreads();
        #pragma unroll
        for (int i = 0; i < 2; i++) {
            int c = tid + i * 256;         // 512 chunks of 8 bf16 per tile
            int row = c >> 2, seg = c & 3;
            *(uint4*)&As[row * LDA + seg * 8] =
                *(const uint4*)&A[(size_t)(m0 + row) * 1024 + kk + seg * 8];
            *(uint4*)&Bs[row * LDA + seg * 8] =
                *(const uint4*)&Bt[(size_t)(n0 + row) * 1024 + kk + seg * 8];
        }
        __syncthreads();

        bf16x8 af[4], bfr[4];
        #pragma unroll
        for (int i = 0; i < 4; i++)
            af[i] = *(const bf16x8*)&As[(wm + i * 16 + ln) * LDA + qd * 8];
        #pragma unroll
        for (int j = 0; j < 4; j++)
            bfr[j] = *(const bf16x8*)&Bs[(wn + j * 16 + ln) * LDA + qd * 8];
        #pragma unroll
        for (int i = 0; i < 4; i++)
            #pragma unroll
            for (int j = 0; j < 4; j++)
                acc[i][j] = __builtin_amdgcn_mfma_f32_16x16x32_bf16(af[i], bfr[j], acc[i][j], 0, 0, 0);
    }

    float bv[4];
    #pragma unroll
    for (int j = 0; j < 4; j++) bv[j] = bias[n0 + wn + j * 16 + ln];

    #pragma unroll
    for (int i = 0; i < 4; i++)
        #pragma unroll
        for (int j = 0; j < 4; j++)
            #pragma unroll
            for (int r = 0; r < 4; r++) {
                int row = m0 + wm + i * 16 + qd * 4 + r;   // C/D: row=(lane>>4)*4+reg
                int col = n0 + wn + j * 16 + ln;           //       col=lane&15
                float val = (acc[i][j][r] + bv[j]) * scale;
                if (MODE == 0) {
                    int b = row >> 11, s = row & 2047, h = col >> 6, d = col & 63;
                    ((uint16_t*)Cout)[(size_t)(b * 16 + h) * 131072 + s * 64 + d] = f2b(val);
                } else {
                    ((float*)Cout)[(size_t)row * 1024 + col] = val;
                }
            }
}

// ---------- flash attention ----------
// Qh/Kh/Vh: bf16 [B*H, S=2048, dk=64]; Of: bf16 flat [B*H, S, dk] (== the buggy reshape rows)
__global__ __launch_bounds__(256, 2)
void attn_kernel(const uint16_t* __restrict__ Qh, const uint16_t* __restrict__ Kh,
                 const uint16_t* __restrict__ Vh, uint16_t* __restrict__ Of) {
    __shared__ uint16_t Ks[64 * 72]  __attribute__((aligned(16)));  // [t][d]
    __shared__ uint16_t Vt[64 * 72]  __attribute__((aligned(16)));  // [d][t]
    __shared__ uint16_t Ps[128 * 72] __attribute__((aligned(16)));  // [q][t] (per-wave 32-row slices)

    const int tid = threadIdx.x;
    const int w = tid >> 6, l = tid & 63, ln = l & 15, qd = l >> 4;
    const size_t base = (size_t)blockIdx.y * 131072;   // (b*16+h)*S*dk
    const int q0 = blockIdx.x * 128;

    // Q fragments live in registers for the whole kernel (A-operand layout)
    bf16x8 qf[2][2];
    #pragma unroll
    for (int tm = 0; tm < 2; tm++)
        #pragma unroll
        for (int ks = 0; ks < 2; ks++)
            qf[tm][ks] = *(const bf16x8*)&Qh[base + (size_t)(q0 + w * 32 + tm * 16 + ln) * 64 + ks * 32 + qd * 8];

    f32x4 oacc[2][4] = {};
    float mrun[2][4], lrun[2][4];
    #pragma unroll
    for (int tm = 0; tm < 2; tm++)
        #pragma unroll
        for (int r = 0; r < 4; r++) { mrun[tm][r] = -__builtin_inff(); lrun[tm][r] = 0.f; }

    for (int j = 0; j < 32; j++) {
        const int t0 = j * 64;
        __syncthreads();
        // stage K [64][64] and V^T [64][64]
        #pragma unroll
        for (int i = 0; i < 2; i++) {
            int c = tid + i * 256;
            {   // K: row-major copy, coalesced
                int tr = c >> 3, seg = c & 7;
                *(uint4*)&Ks[tr * 72 + seg * 8] =
                    *(const uint4*)&Kh[base + (size_t)(t0 + tr) * 64 + seg * 8];
            }
            {   // V: transpose during staging (lane-major over t -> conflict-free LDS rows)
                int t = c & 63, seg = c >> 6;
                U16x8 uu; uu.u = *(const uint4*)&Vh[base + (size_t)(t0 + t) * 64 + seg * 8];
                #pragma unroll
                for (int e = 0; e < 8; e++) Vt[(seg * 8 + e) * 72 + t] = uu.s[e];
            }
        }
        __syncthreads();

        // S = Q K^T  (k over dk=64: 2 MFMA k-steps)
        f32x4 sa[2][4] = {};
        bf16x8 kb[4][2];
        #pragma unroll
        for (int tn = 0; tn < 4; tn++)
            #pragma unroll
            for (int ks = 0; ks < 2; ks++)
                kb[tn][ks] = *(const bf16x8*)&Ks[(tn * 16 + ln) * 72 + ks * 32 + qd * 8];
        #pragma unroll
        for (int tm = 0; tm < 2; tm++)
            #pragma unroll
            for (int tn = 0; tn < 4; tn++)
                #pragma unroll
                for (int ks = 0; ks < 2; ks++)
                    sa[tm][tn] = __builtin_amdgcn_mfma_f32_16x16x32_bf16(qf[tm][ks], kb[tn][ks], sa[tm][tn], 0, 0, 0);

        // online softmax (rows live in (quad,reg); cols across 16-lane group + 4 tn)
        #pragma unroll
        for (int tm = 0; tm < 2; tm++)
            #pragma unroll
            for (int r = 0; r < 4; r++) {
                float mx = fmaxf(fmaxf(sa[tm][0][r], sa[tm][1][r]), fmaxf(sa[tm][2][r], sa[tm][3][r]));
                mx = fmaxf(mx, __shfl_xor(mx, 1));
                mx = fmaxf(mx, __shfl_xor(mx, 2));
                mx = fmaxf(mx, __shfl_xor(mx, 4));
                mx = fmaxf(mx, __shfl_xor(mx, 8));
                float mnew = fmaxf(mrun[tm][r], mx);
                float alpha = __expf(mrun[tm][r] - mnew);
                mrun[tm][r] = mnew;
                float rs = 0.f;
                #pragma unroll
                for (int tn = 0; tn < 4; tn++) {
                    float p = __expf(sa[tm][tn][r] - mnew);
                    sa[tm][tn][r] = p; rs += p;
                }
                rs += __shfl_xor(rs, 1);
                rs += __shfl_xor(rs, 2);
                rs += __shfl_xor(rs, 4);
                rs += __shfl_xor(rs, 8);
                lrun[tm][r] = lrun[tm][r] * alpha + rs;
                #pragma unroll
                for (int dt = 0; dt < 4; dt++) oacc[tm][dt][r] *= alpha;
                // P: C-layout -> LDS (round-trip to reach A-operand layout)
                #pragma unroll
                for (int tn = 0; tn < 4; tn++)
                    Ps[(w * 32 + tm * 16 + qd * 4 + r) * 72 + tn * 16 + ln] = f2b(sa[tm][tn][r]);
            }

        // O += P V   (Ps region is wave-private: no barrier needed, same-wave RAW handled by waitcnt)
        bf16x8 pa[2][2], vb[4][2];
        #pragma unroll
        for (int tm = 0; tm < 2; tm++)
            #pragma unroll
            for (int ks = 0; ks < 2; ks++)
                pa[tm][ks] = *(const bf16x8*)&Ps[(w * 32 + tm * 16 + ln) * 72 + ks * 32 + qd * 8];
        #pragma unroll
        for (int dt = 0; dt < 4; dt++)
            #pragma unroll
            for (int ks = 0; ks < 2; ks++)
                vb[dt][ks] = *(const bf16x8*)&Vt[(dt * 16 + ln) * 72 + ks * 32 + qd * 8];
        #pragma unroll
        for (int tm = 0; tm < 2; tm++)
            #pragma unroll
            for (int dt = 0; dt < 4; dt++)
                #pragma unroll
                for (int ks = 0; ks < 2; ks++)
                    oacc[tm][dt] = __builtin_amdgcn_mfma_f32_16x16x32_bf16(pa[tm][ks], vb[dt][ks], oacc[tm][dt], 0, 0, 0);
    }

    // normalize, bounce through LDS for coalesced 16B global stores
    #pragma unroll
    for (int tm = 0; tm < 2; tm++)
        #pragma unroll
        for (int r = 0; r < 4; r++) {
            float inv = 1.0f / lrun[tm][r];
            #pragma unroll
            for (int dt = 0; dt < 4; dt++)
                Ps[(w * 32 + tm * 16 + qd * 4 + r) * 72 + dt * 16 + ln] = f2b(oacc[tm][dt][r] * inv);
        }
    __syncthreads();
    #pragma unroll
    for (int i = 0; i < 4; i++) {
        int c = tid + i * 256;
        int row = c >> 3, seg = c & 7;
        *(uint4*)&Of[base + (size_t)(q0 + row) * 64 + seg * 8] =
            *(const uint4*)&Ps[row * 72 + seg * 8];
    }
}

// ---------- launch ----------
extern "C" void kernel_launch(void* const* d_in, const int* in_sizes, int n_in,
                              void* d_out, int out_size, void* d_ws, size_t ws_size,
                              hipStream_t stream) {
    const float* q   = (const float*)d_in[0];
    const float* k   = (const float*)d_in[1];
    const float* v   = (const float*)d_in[2];
    const float* w_q = (const float*)d_in[3];
    const float* b_q = (const float*)d_in[4];
    const float* w_k = (const float*)d_in[5];
    const float* b_k = (const float*)d_in[6];
    const float* w_v = (const float*)d_in[7];
    const float* b_v = (const float*)d_in[8];
    const float* w_0 = (const float*)d_in[9];
    const float* b_0 = (const float*)d_in[10];

    // ws layout (uint16 elements): 4x 1M weightsT + Qh/Kh/Vh/Pf/xb (8M each) = 92.3 MB
    uint16_t* ws  = (uint16_t*)d_ws;
    const size_t WE = 1048576, NE = 8388608;
    uint16_t* wtq = ws;
    uint16_t* wtk = wtq + WE;
    uint16_t* wtv = wtk + WE;
    uint16_t* wt0 = wtv + WE;
    uint16_t* Qh  = wt0 + WE;
    uint16_t* Kh  = Qh + NE;
    uint16_t* Vh  = Kh + NE;
    uint16_t* Pf  = Vh + NE;
    uint16_t* xb  = Pf + NE;

    const dim3 tb(256);
    const dim3 gT(16, 16);       // weight transpose tiles
    const dim3 gG(8, 64);        // GEMM: N/128 x M/128
    const dim3 gA(16, 64);       // attn: S/128 x B*H
    const int  n4 = 2097152;     // 8M floats / 4

    transpose_cast<<<gT, tb, 0, stream>>>(w_q, wtq);
    transpose_cast<<<gT, tb, 0, stream>>>(w_k, wtk);
    transpose_cast<<<gT, tb, 0, stream>>>(w_v, wtv);
    transpose_cast<<<gT, tb, 0, stream>>>(w_0, wt0);

    cast_f32_bf16<<<8192, tb, 0, stream>>>(q, xb, n4);
    gemm_bt<0><<<gG, tb, 0, stream>>>(xb, wtq, b_q, Qh, 0.125f);   // fold 1/sqrt(dk) into Q

    cast_f32_bf16<<<8192, tb, 0, stream>>>(k, xb, n4);
    gemm_bt<0><<<gG, tb, 0, stream>>>(xb, wtk, b_k, Kh, 1.0f);

    cast_f32_bf16<<<8192, tb, 0, stream>>>(v, xb, n4);
    gemm_bt<0><<<gG, tb, 0, stream>>>(xb, wtv, b_v, Vh, 1.0f);

    attn_kernel<<<gA, tb, 0, stream>>>(Qh, Kh, Vh, Pf);

    gemm_bt<1><<<gG, tb, 0, stream>>>(Pf, wt0, b_0, d_out, 1.0f);
}

// Round 3
// 423.844 us; speedup vs baseline: 1.3240x; 1.3240x over previous
//
#include <hip/hip_runtime.h>
#include <stdint.h>

// ---------- types ----------
typedef __bf16 bf16x8 __attribute__((ext_vector_type(8)));
typedef float  f32x4  __attribute__((ext_vector_type(4)));

union U16x8 { uint4 u; uint16_t s[8]; };

__device__ __forceinline__ uint16_t f2b(float f) {
    union { float f; uint32_t u; } c; c.f = f;
    uint32_t u = c.u;
    uint32_t r = u + 0x7fffu + ((u >> 16) & 1u);   // round-to-nearest-even
    return (uint16_t)(r >> 16);
}

// async global->LDS, 16B per lane. LDS dest is wave-uniform base + lane*16:
// callers must pass per-lane lds ptrs that are contiguous in lane order.
__device__ __forceinline__ void gl_lds16(const uint16_t* g, uint16_t* l) {
    __builtin_amdgcn_global_load_lds(
        (const __attribute__((address_space(1))) void*)g,
        (__attribute__((address_space(3))) void*)l, 16, 0, 0);
}

// ---------- prep kernels ----------
__global__ void cast_f32_bf16(const float* __restrict__ x, uint16_t* __restrict__ y, int n4) {
    int i = blockIdx.x * blockDim.x + threadIdx.x;
    if (i < n4) {
        float4 v = ((const float4*)x)[i];
        ushort4 o;
        o.x = f2b(v.x); o.y = f2b(v.y); o.z = f2b(v.z); o.w = f2b(v.w);
        *(ushort4*)(y + (size_t)i * 4) = o;
    }
}

// 4 weights [1024,1024] fp32 [k][n] -> bf16 [n][k], one launch (z selects weight)
__global__ void transpose_cast4(const float* __restrict__ W0, const float* __restrict__ W1,
                                const float* __restrict__ W2, const float* __restrict__ W3,
                                uint16_t* __restrict__ O0, uint16_t* __restrict__ O1,
                                uint16_t* __restrict__ O2, uint16_t* __restrict__ O3) {
    __shared__ float tile[64][65];
    const float* W; uint16_t* Wt;
    switch (blockIdx.z) {
        case 0: W = W0; Wt = O0; break;
        case 1: W = W1; Wt = O1; break;
        case 2: W = W2; Wt = O2; break;
        default: W = W3; Wt = O3; break;
    }
    const int k0 = blockIdx.y * 64, n0 = blockIdx.x * 64;
    const int tx = threadIdx.x & 63, ty = threadIdx.x >> 6;
    #pragma unroll
    for (int r = ty; r < 64; r += 4)
        tile[r][tx] = W[(size_t)(k0 + r) * 1024 + n0 + tx];
    __syncthreads();
    #pragma unroll
    for (int r = ty; r < 64; r += 4)
        Wt[(size_t)(n0 + r) * 1024 + k0 + tx] = f2b(tile[tx][r]);
}

// ---------- GEMM: C[8192,1024] = A[M,K](bf16) * Bt[N,K](bf16) + bias ----------
// m97 pattern: unpadded 128x32 LDS tiles, global_load_lds width=16 staging.
// MODE 0: out bf16 head-split [B,H,S,dk]; MODE 1: out fp32 [M,N] row-major.
template <int MODE>
__global__ __launch_bounds__(256, 2)
void gemm_bt(const uint16_t* __restrict__ A, const uint16_t* __restrict__ Bt,
             const float* __restrict__ bias, void* __restrict__ Cout, float scale) {
    __shared__ uint16_t SH[2 * 128 * 32] __attribute__((aligned(16)));
    uint16_t* As = SH;
    uint16_t* Bs = SH + 128 * 32;

    const int tid = threadIdx.x;
    const int m0 = blockIdx.y * 128, n0 = blockIdx.x * 128;
    const int l = tid & 63, ln = l & 15, qd = l >> 4;
    const int w = tid >> 6;
    const int wm = (w >> 1) * 64, wn = (w & 1) * 64;

    f32x4 acc[4][4] = {};

    for (int kk = 0; kk < 1024; kk += 32) {
        __syncthreads();
        #pragma unroll
        for (int i = 0; i < 2; i++) {
            int c = tid + i * 256;           // 512 chunks of 8 bf16 per tile
            // LDS elem offset c*8 == byte c*16: lane-contiguous within each wave
            gl_lds16(&A[(size_t)(m0 + (c >> 2)) * 1024 + kk + (c & 3) * 8], &As[c * 8]);
            gl_lds16(&Bt[(size_t)(n0 + (c >> 2)) * 1024 + kk + (c & 3) * 8], &Bs[c * 8]);
        }
        __syncthreads();                     // drains vmcnt(0): tiles visible

        bf16x8 af[4], bfr[4];
        #pragma unroll
        for (int i = 0; i < 4; i++)
            af[i] = *(const bf16x8*)&As[(wm + i * 16 + ln) * 32 + qd * 8];
        #pragma unroll
        for (int j = 0; j < 4; j++)
            bfr[j] = *(const bf16x8*)&Bs[(wn + j * 16 + ln) * 32 + qd * 8];
        #pragma unroll
        for (int i = 0; i < 4; i++)
            #pragma unroll
            for (int j = 0; j < 4; j++)
                acc[i][j] = __builtin_amdgcn_mfma_f32_16x16x32_bf16(af[i], bfr[j], acc[i][j], 0, 0, 0);
    }

    float bv[4];
    #pragma unroll
    for (int j = 0; j < 4; j++) bv[j] = bias[n0 + wn + j * 16 + ln];

    __syncthreads();                         // done reading As/Bs; reuse as epilogue scratch

    if (MODE == 1) {
        float* scr = (float*)SH + w * 1024;  // per-wave 16x64 f32 patch
        #pragma unroll
        for (int i = 0; i < 4; i++) {
            #pragma unroll
            for (int j = 0; j < 4; j++)
                #pragma unroll
                for (int r = 0; r < 4; r++)
                    scr[(qd * 4 + r) * 64 + j * 16 + ln] = (acc[i][j][r] + bv[j]) * scale;
            #pragma unroll
            for (int ii = 0; ii < 4; ii++) {
                int ch = ii * 64 + l, row = ch >> 4, sg = ch & 15;
                *(float4*)&((float*)Cout)[(size_t)(m0 + wm + i * 16 + row) * 1024 + n0 + wn + sg * 4] =
                    *(float4*)&scr[row * 64 + sg * 4];
            }
        }
    } else {
        uint16_t* scr = (uint16_t*)SH + w * 1024;  // per-wave 16x64 bf16 patch
        const int colb = n0 + wn;
        const int h = colb >> 6;                   // 64-col patch stays in one head
        #pragma unroll
        for (int i = 0; i < 4; i++) {
            #pragma unroll
            for (int j = 0; j < 4; j++)
                #pragma unroll
                for (int r = 0; r < 4; r++)
                    scr[(qd * 4 + r) * 64 + j * 16 + ln] = f2b((acc[i][j][r] + bv[j]) * scale);
            #pragma unroll
            for (int ii = 0; ii < 2; ii++) {
                int ch = ii * 64 + l, row = ch >> 3, sg = ch & 7;
                int grow = m0 + wm + i * 16 + row;
                int b = grow >> 11, s = grow & 2047;
                int d = sg * 8;
                *(uint4*)&((uint16_t*)Cout)[(size_t)((b * 16 + h) * 2048 + s) * 64 + d] =
                    *(uint4*)&scr[row * 64 + sg * 8];
            }
        }
    }
}

// ---------- flash attention (S^T formulation) ----------
// Qh/Kh/Vh: bf16 [B*H, 2048, 64]; Of: bf16 flat [B*H, S, dk]
__global__ __launch_bounds__(256, 4)
void attn_kernel(const uint16_t* __restrict__ Qh, const uint16_t* __restrict__ Kh,
                 const uint16_t* __restrict__ Vh, uint16_t* __restrict__ Of) {
    __shared__ uint16_t Ks[64 * 72]  __attribute__((aligned(16)));  // [t][d]
    __shared__ uint16_t Vt[64 * 72]  __attribute__((aligned(16)));  // [d][t]
    __shared__ uint16_t Ps[128 * 72] __attribute__((aligned(16)));  // [q][t], per-wave rows

    const int tid = threadIdx.x;
    const int w = tid >> 6, l = tid & 63, ln = l & 15, qd = l >> 4;
    const size_t base = (size_t)blockIdx.y * 131072;
    const int q0 = blockIdx.x * 128;

    // Q fragments (B-operand now): [n=q][k=d]
    bf16x8 qf[2][2];
    #pragma unroll
    for (int tq = 0; tq < 2; tq++)
        #pragma unroll
        for (int ks = 0; ks < 2; ks++)
            qf[tq][ks] = *(const bf16x8*)&Qh[base + (size_t)(q0 + w * 32 + tq * 16 + ln) * 64 + ks * 32 + qd * 8];

    f32x4 oacc[2][4] = {};
    float mrun[2] = { -__builtin_inff(), -__builtin_inff() };
    float lrun[2] = { 0.f, 0.f };

    for (int j = 0; j < 32; j++) {
        const int t0 = j * 64;
        __syncthreads();
        // K: row-major b128 copy
        #pragma unroll
        for (int i = 0; i < 2; i++) {
            int c = tid + i * 256, tr = c >> 3, sg = c & 7;
            *(uint4*)&Ks[tr * 72 + sg * 8] =
                *(const uint4*)&Kh[base + (size_t)(t0 + tr) * 64 + sg * 8];
        }
        // V: transpose via t-pairing -> packed b32 LDS writes
        {
            int u = tid & 31, sg = tid >> 5;   // u: t-pair, sg: 8-d segment
            U16x8 r0, r1;
            r0.u = *(const uint4*)&Vh[base + (size_t)(t0 + 2 * u) * 64 + sg * 8];
            r1.u = *(const uint4*)&Vh[base + (size_t)(t0 + 2 * u + 1) * 64 + sg * 8];
            #pragma unroll
            for (int e = 0; e < 8; e++) {
                uint32_t pk = (uint32_t)r0.s[e] | ((uint32_t)r1.s[e] << 16);
                *(uint32_t*)&Vt[(sg * 8 + e) * 72 + 2 * u] = pk;
            }
        }
        __syncthreads();

        // S^T = K Q^T : C-layout gives row=t=(qd*4+r), col=q=ln
        bf16x8 kb[4][2];
        #pragma unroll
        for (int tt = 0; tt < 4; tt++)
            #pragma unroll
            for (int ks = 0; ks < 2; ks++)
                kb[tt][ks] = *(const bf16x8*)&Ks[(tt * 16 + ln) * 72 + ks * 32 + qd * 8];
        f32x4 sa[4][2] = {};
        #pragma unroll
        for (int tt = 0; tt < 4; tt++)
            #pragma unroll
            for (int tq = 0; tq < 2; tq++)
                #pragma unroll
                for (int ks = 0; ks < 2; ks++)
                    sa[tt][tq] = __builtin_amdgcn_mfma_f32_16x16x32_bf16(kb[tt][ks], qf[tq][ks], sa[tt][tq], 0, 0, 0);

        // online softmax: per lane ONE q per tq (q=ln), 16 t-values in-lane + qd cross-lane
        float alpha[2];
        #pragma unroll
        for (int tq = 0; tq < 2; tq++) {
            float mx = -__builtin_inff();
            #pragma unroll
            for (int tt = 0; tt < 4; tt++)
                #pragma unroll
                for (int r = 0; r < 4; r++) mx = fmaxf(mx, sa[tt][tq][r]);
            mx = fmaxf(mx, __shfl_xor(mx, 16));
            mx = fmaxf(mx, __shfl_xor(mx, 32));
            float mnew = fmaxf(mrun[tq], mx);
            alpha[tq] = __expf(mrun[tq] - mnew);
            mrun[tq] = mnew;
            float rs = 0.f;
            #pragma unroll
            for (int tt = 0; tt < 4; tt++) {
                #pragma unroll
                for (int r = 0; r < 4; r++) {
                    float p = __expf(sa[tt][tq][r] - mnew);
                    sa[tt][tq][r] = p; rs += p;
                }
            }
            rs += __shfl_xor(rs, 16);
            rs += __shfl_xor(rs, 32);
            lrun[tq] = lrun[tq] * alpha[tq] + rs;
            // P^T -> Ps [q][t]: 4 consecutive t per lane -> packed b64 writes
            #pragma unroll
            for (int tt = 0; tt < 4; tt++) {
                ushort4 o;
                o.x = f2b(sa[tt][tq][0]); o.y = f2b(sa[tt][tq][1]);
                o.z = f2b(sa[tt][tq][2]); o.w = f2b(sa[tt][tq][3]);
                *(ushort4*)&Ps[(w * 32 + tq * 16 + ln) * 72 + tt * 16 + qd * 4] = o;
            }
        }

        // rescale O by alpha (broadcast: alpha is quad-uniform, lane qd*4+r holds q=qd*4+r)
        #pragma unroll
        for (int tm = 0; tm < 2; tm++)
            #pragma unroll
            for (int r = 0; r < 4; r++) {
                float ab = __shfl(alpha[tm], qd * 4 + r);
                #pragma unroll
                for (int dt = 0; dt < 4; dt++) oacc[tm][dt][r] *= ab;
            }

        // O += P V  (Ps rows are wave-private; same-wave DS ops execute in order)
        bf16x8 pa[2][2], vb[4][2];
        #pragma unroll
        for (int tm = 0; tm < 2; tm++)
            #pragma unroll
            for (int ks = 0; ks < 2; ks++)
                pa[tm][ks] = *(const bf16x8*)&Ps[(w * 32 + tm * 16 + ln) * 72 + ks * 32 + qd * 8];
        #pragma unroll
        for (int dt = 0; dt < 4; dt++)
            #pragma unroll
            for (int ks = 0; ks < 2; ks++)
                vb[dt][ks] = *(const bf16x8*)&Vt[(dt * 16 + ln) * 72 + ks * 32 + qd * 8];
        #pragma unroll
        for (int tm = 0; tm < 2; tm++)
            #pragma unroll
            for (int dt = 0; dt < 4; dt++)
                #pragma unroll
                for (int ks = 0; ks < 2; ks++)
                    oacc[tm][dt] = __builtin_amdgcn_mfma_f32_16x16x32_bf16(pa[tm][ks], vb[dt][ks], oacc[tm][dt], 0, 0, 0);
    }

    // normalize + coalesced store via LDS bounce
    float inv[2] = { 1.0f / lrun[0], 1.0f / lrun[1] };
    #pragma unroll
    for (int tm = 0; tm < 2; tm++)
        #pragma unroll
        for (int r = 0; r < 4; r++) {
            float iv = __shfl(inv[tm], qd * 4 + r);
            #pragma unroll
            for (int dt = 0; dt < 4; dt++)
                Ps[(w * 32 + tm * 16 + qd * 4 + r) * 72 + dt * 16 + ln] = f2b(oacc[tm][dt][r] * iv);
        }
    __syncthreads();
    #pragma unroll
    for (int i = 0; i < 4; i++) {
        int c = tid + i * 256, row = c >> 3, sg = c & 7;
        *(uint4*)&Of[base + (size_t)(q0 + row) * 64 + sg * 8] =
            *(const uint4*)&Ps[row * 72 + sg * 8];
    }
}

// ---------- launch ----------
extern "C" void kernel_launch(void* const* d_in, const int* in_sizes, int n_in,
                              void* d_out, int out_size, void* d_ws, size_t ws_size,
                              hipStream_t stream) {
    const float* q   = (const float*)d_in[0];
    const float* k   = (const float*)d_in[1];
    const float* v   = (const float*)d_in[2];
    const float* w_q = (const float*)d_in[3];
    const float* b_q = (const float*)d_in[4];
    const float* w_k = (const float*)d_in[5];
    const float* b_k = (const float*)d_in[6];
    const float* w_v = (const float*)d_in[7];
    const float* b_v = (const float*)d_in[8];
    const float* w_0 = (const float*)d_in[9];
    const float* b_0 = (const float*)d_in[10];

    uint16_t* ws  = (uint16_t*)d_ws;
    const size_t WE = 1048576, NE = 8388608;
    uint16_t* wtq = ws;
    uint16_t* wtk = wtq + WE;
    uint16_t* wtv = wtk + WE;
    uint16_t* wt0 = wtv + WE;
    uint16_t* Qh  = wt0 + WE;
    uint16_t* Kh  = Qh + NE;
    uint16_t* Vh  = Kh + NE;
    uint16_t* Pf  = Vh + NE;
    uint16_t* xb  = Pf + NE;

    const dim3 tb(256);
    const dim3 gT(16, 16, 4);    // all 4 weight transposes in one launch
    const dim3 gG(8, 64);        // GEMM: N/128 x M/128
    const dim3 gA(16, 64);       // attn: S/128 x B*H
    const int  n4 = 2097152;

    transpose_cast4<<<gT, tb, 0, stream>>>(w_q, w_k, w_v, w_0, wtq, wtk, wtv, wt0);

    cast_f32_bf16<<<8192, tb, 0, stream>>>(q, xb, n4);
    gemm_bt<0><<<gG, tb, 0, stream>>>(xb, wtq, b_q, Qh, 0.125f);

    cast_f32_bf16<<<8192, tb, 0, stream>>>(k, xb, n4);
    gemm_bt<0><<<gG, tb, 0, stream>>>(xb, wtk, b_k, Kh, 1.0f);

    cast_f32_bf16<<<8192, tb, 0, stream>>>(v, xb, n4);
    gemm_bt<0><<<gG, tb, 0, stream>>>(xb, wtv, b_v, Vh, 1.0f);

    attn_kernel<<<gA, tb, 0, stream>>>(Qh, Kh, Vh, Pf);

    gemm_bt<1><<<gG, tb, 0, stream>>>(Pf, wt0, b_0, d_out, 1.0f);
}

// Round 4
// 387.250 us; speedup vs baseline: 1.4491x; 1.0945x over previous
//
#include <hip/hip_runtime.h>
#include <stdint.h>

// ---------- types ----------
typedef __bf16 bf16x8 __attribute__((ext_vector_type(8)));
typedef float  f32x4  __attribute__((ext_vector_type(4)));

union U16x8 { uint4 u; uint16_t s[8]; };

__device__ __forceinline__ uint16_t f2b(float f) {
    union { float f; uint32_t u; } c; c.f = f;
    uint32_t u = c.u;
    uint32_t r = u + 0x7fffu + ((u >> 16) & 1u);   // round-to-nearest-even
    return (uint16_t)(r >> 16);
}

__device__ __forceinline__ uint32_t asu(float f) {
    union { float f; uint32_t u; } c; c.f = f; return c.u;
}
// pack two f32 -> two bf16 (half-up rounding), lo = a, hi = b
__device__ __forceinline__ uint32_t pack_bf16_hu(float a, float b) {
    uint32_t ua = asu(a) + 0x8000u, ub = asu(b) + 0x8000u;
    return (ua >> 16) | (ub & 0xffff0000u);        // v_lshr + v_and_or
}

// async global->LDS, 16B per lane; dest must be lane-contiguous
__device__ __forceinline__ void gl_lds16(const uint16_t* g, uint16_t* l) {
    __builtin_amdgcn_global_load_lds(
        (const __attribute__((address_space(1))) void*)g,
        (__attribute__((address_space(3))) void*)l, 16, 0, 0);
}

// ---------- prep kernels ----------
// q,k,v fp32 -> bf16 in one launch (y selects tensor)
__global__ void cast3_f32_bf16(const float* __restrict__ x0, const float* __restrict__ x1,
                               const float* __restrict__ x2,
                               uint16_t* __restrict__ y0, uint16_t* __restrict__ y1,
                               uint16_t* __restrict__ y2, int n4) {
    const float* x; uint16_t* y;
    switch (blockIdx.y) {
        case 0: x = x0; y = y0; break;
        case 1: x = x1; y = y1; break;
        default: x = x2; y = y2; break;
    }
    int i = blockIdx.x * blockDim.x + threadIdx.x;
    if (i < n4) {
        float4 v = ((const float4*)x)[i];
        ushort4 o;
        o.x = f2b(v.x); o.y = f2b(v.y); o.z = f2b(v.z); o.w = f2b(v.w);
        *(ushort4*)(y + (size_t)i * 4) = o;
    }
}

// 4 weights [1024,1024] fp32 [k][n] -> bf16 [n][k], one launch (z selects weight)
__global__ void transpose_cast4(const float* __restrict__ W0, const float* __restrict__ W1,
                                const float* __restrict__ W2, const float* __restrict__ W3,
                                uint16_t* __restrict__ O0, uint16_t* __restrict__ O1,
                                uint16_t* __restrict__ O2, uint16_t* __restrict__ O3) {
    __shared__ float tile[64][65];
    const float* W; uint16_t* Wt;
    switch (blockIdx.z) {
        case 0: W = W0; Wt = O0; break;
        case 1: W = W1; Wt = O1; break;
        case 2: W = W2; Wt = O2; break;
        default: W = W3; Wt = O3; break;
    }
    const int k0 = blockIdx.y * 64, n0 = blockIdx.x * 64;
    const int tx = threadIdx.x & 63, ty = threadIdx.x >> 6;
    #pragma unroll
    for (int r = ty; r < 64; r += 4)
        tile[r][tx] = W[(size_t)(k0 + r) * 1024 + n0 + tx];
    __syncthreads();
    #pragma unroll
    for (int r = ty; r < 64; r += 4)
        Wt[(size_t)(n0 + r) * 1024 + k0 + tx] = f2b(tile[tx][r]);
}

// ---------- fused QKV projection GEMM ----------
// C[8192,1024] = A[M,K](bf16) * Bt[N,K](bf16) + bias, out bf16 head-split [B,H,S,dk]
// blockIdx.z picks (A, Bt, bias, out); z==0 (Q) applies qscale.
__global__ __launch_bounds__(256, 3)
void gemm_qkv(const uint16_t* __restrict__ A0, const uint16_t* __restrict__ A1,
              const uint16_t* __restrict__ A2,
              const uint16_t* __restrict__ B0, const uint16_t* __restrict__ B1,
              const uint16_t* __restrict__ B2,
              const float* __restrict__ c0, const float* __restrict__ c1,
              const float* __restrict__ c2,
              uint16_t* __restrict__ O0, uint16_t* __restrict__ O1,
              uint16_t* __restrict__ O2, float qscale) {
    __shared__ uint16_t SH[2 * 128 * 32] __attribute__((aligned(16)));
    uint16_t* As = SH;
    uint16_t* Bs = SH + 128 * 32;

    const uint16_t* A; const uint16_t* Bt; const float* bias; uint16_t* Cout; float scale;
    switch (blockIdx.z) {
        case 0: A = A0; Bt = B0; bias = c0; Cout = O0; scale = qscale; break;
        case 1: A = A1; Bt = B1; bias = c1; Cout = O1; scale = 1.0f;  break;
        default: A = A2; Bt = B2; bias = c2; Cout = O2; scale = 1.0f; break;
    }

    const int tid = threadIdx.x;
    const int m0 = blockIdx.y * 128, n0 = blockIdx.x * 128;
    const int l = tid & 63, ln = l & 15, qd = l >> 4;
    const int w = tid >> 6;
    const int wm = (w >> 1) * 64, wn = (w & 1) * 64;

    f32x4 acc[4][4] = {};

    for (int kk = 0; kk < 1024; kk += 32) {
        __syncthreads();
        #pragma unroll
        for (int i = 0; i < 2; i++) {
            int c = tid + i * 256;           // 512 chunks of 8 bf16 per tile
            gl_lds16(&A[(size_t)(m0 + (c >> 2)) * 1024 + kk + (c & 3) * 8], &As[c * 8]);
            gl_lds16(&Bt[(size_t)(n0 + (c >> 2)) * 1024 + kk + (c & 3) * 8], &Bs[c * 8]);
        }
        __syncthreads();

        bf16x8 af[4], bfr[4];
        #pragma unroll
        for (int i = 0; i < 4; i++)
            af[i] = *(const bf16x8*)&As[(wm + i * 16 + ln) * 32 + qd * 8];
        #pragma unroll
        for (int j = 0; j < 4; j++)
            bfr[j] = *(const bf16x8*)&Bs[(wn + j * 16 + ln) * 32 + qd * 8];
        #pragma unroll
        for (int i = 0; i < 4; i++)
            #pragma unroll
            for (int j = 0; j < 4; j++)
                acc[i][j] = __builtin_amdgcn_mfma_f32_16x16x32_bf16(af[i], bfr[j], acc[i][j], 0, 0, 0);
    }

    float bv[4];
    #pragma unroll
    for (int j = 0; j < 4; j++) bv[j] = bias[n0 + wn + j * 16 + ln];

    __syncthreads();
    uint16_t* scr = (uint16_t*)SH + w * 1024;      // per-wave 16x64 bf16 patch
    const int colb = n0 + wn;
    const int h = colb >> 6;
    #pragma unroll
    for (int i = 0; i < 4; i++) {
        #pragma unroll
        for (int j = 0; j < 4; j++)
            #pragma unroll
            for (int r = 0; r < 4; r++)
                scr[(qd * 4 + r) * 64 + j * 16 + ln] = f2b((acc[i][j][r] + bv[j]) * scale);
        #pragma unroll
        for (int ii = 0; ii < 2; ii++) {
            int ch = ii * 64 + l, row = ch >> 3, sg = ch & 7;
            int grow = m0 + wm + i * 16 + row;
            int b = grow >> 11, s = grow & 2047;
            *(uint4*)&Cout[(size_t)((b * 16 + h) * 2048 + s) * 64 + sg * 8] =
                *(uint4*)&scr[row * 64 + sg * 8];
        }
    }
}

// ---------- output projection GEMM (fp32 out) ----------
__global__ __launch_bounds__(256, 3)
void gemm_o(const uint16_t* __restrict__ A, const uint16_t* __restrict__ Bt,
            const float* __restrict__ bias, float* __restrict__ Cout) {
    __shared__ uint16_t SH[2 * 128 * 32] __attribute__((aligned(16)));
    uint16_t* As = SH;
    uint16_t* Bs = SH + 128 * 32;

    const int tid = threadIdx.x;
    const int m0 = blockIdx.y * 128, n0 = blockIdx.x * 128;
    const int l = tid & 63, ln = l & 15, qd = l >> 4;
    const int w = tid >> 6;
    const int wm = (w >> 1) * 64, wn = (w & 1) * 64;

    f32x4 acc[4][4] = {};

    for (int kk = 0; kk < 1024; kk += 32) {
        __syncthreads();
        #pragma unroll
        for (int i = 0; i < 2; i++) {
            int c = tid + i * 256;
            gl_lds16(&A[(size_t)(m0 + (c >> 2)) * 1024 + kk + (c & 3) * 8], &As[c * 8]);
            gl_lds16(&Bt[(size_t)(n0 + (c >> 2)) * 1024 + kk + (c & 3) * 8], &Bs[c * 8]);
        }
        __syncthreads();

        bf16x8 af[4], bfr[4];
        #pragma unroll
        for (int i = 0; i < 4; i++)
            af[i] = *(const bf16x8*)&As[(wm + i * 16 + ln) * 32 + qd * 8];
        #pragma unroll
        for (int j = 0; j < 4; j++)
            bfr[j] = *(const bf16x8*)&Bs[(wn + j * 16 + ln) * 32 + qd * 8];
        #pragma unroll
        for (int i = 0; i < 4; i++)
            #pragma unroll
            for (int j = 0; j < 4; j++)
                acc[i][j] = __builtin_amdgcn_mfma_f32_16x16x32_bf16(af[i], bfr[j], acc[i][j], 0, 0, 0);
    }

    float bv[4];
    #pragma unroll
    for (int j = 0; j < 4; j++) bv[j] = bias[n0 + wn + j * 16 + ln];

    __syncthreads();
    float* scr = (float*)SH + w * 1024;            // per-wave 16x64 f32 patch
    #pragma unroll
    for (int i = 0; i < 4; i++) {
        #pragma unroll
        for (int j = 0; j < 4; j++)
            #pragma unroll
            for (int r = 0; r < 4; r++)
                scr[(qd * 4 + r) * 64 + j * 16 + ln] = acc[i][j][r] + bv[j];
        #pragma unroll
        for (int ii = 0; ii < 4; ii++) {
            int ch = ii * 64 + l, row = ch >> 4, sg = ch & 15;
            *(float4*)&Cout[(size_t)(m0 + wm + i * 16 + row) * 1024 + n0 + wn + sg * 4] =
                *(float4*)&scr[row * 64 + sg * 4];
        }
    }
}

// ---------- flash attention (S^T and O^T formulation) ----------
// Qh holds log2e-scaled Q. 512 threads, 256-row Q tile, K/V staged once per 8 waves.
// O^T = V^T * P^T puts col=q in C-layout: softmax state needs NO cross-lane broadcast.
__global__ __launch_bounds__(512, 4)
void attn_kernel(const uint16_t* __restrict__ Qh, const uint16_t* __restrict__ Kh,
                 const uint16_t* __restrict__ Vh, uint16_t* __restrict__ Of) {
    __shared__ uint16_t Ks[64 * 72]  __attribute__((aligned(16)));  // [t][d]
    __shared__ uint16_t Vt[64 * 72]  __attribute__((aligned(16)));  // [d][t]
    __shared__ uint16_t Ps[256 * 72] __attribute__((aligned(16)));  // [q][t], per-wave 32 rows

    const int tid = threadIdx.x;
    const int w = tid >> 6, l = tid & 63, ln = l & 15, qd = l >> 4;
    const size_t base = (size_t)blockIdx.y * 131072;
    const int q0 = blockIdx.x * 256;

    // Q fragments (B-operand): [n=q][k=d]
    bf16x8 qf[2][2];
    #pragma unroll
    for (int tq = 0; tq < 2; tq++)
        #pragma unroll
        for (int ks = 0; ks < 2; ks++)
            qf[tq][ks] = *(const bf16x8*)&Qh[base + (size_t)(q0 + w * 32 + tq * 16 + ln) * 64 + ks * 32 + qd * 8];

    f32x4 oacc[2][4] = {};                          // [tq][dt], O^T: row=d, col=q
    float mrun[2] = { -__builtin_inff(), -__builtin_inff() };
    float lrun[2] = { 0.f, 0.f };

    for (int j = 0; j < 32; j++) {
        const int t0 = j * 64;
        __syncthreads();
        if (w >= 4) {
            // K staging: waves 4-7 (256 threads), 2 b128 chunks each
            int idx = tid - 256;
            #pragma unroll
            for (int i = 0; i < 2; i++) {
                int c = idx + i * 256, tr = c >> 3, sg = c & 7;
                *(uint4*)&Ks[tr * 72 + sg * 8] =
                    *(const uint4*)&Kh[base + (size_t)(t0 + tr) * 64 + sg * 8];
            }
        } else {
            // V transpose staging: waves 0-3, t-pair packing -> b32 writes
            int u = tid & 31, sg = tid >> 5;
            U16x8 r0, r1;
            r0.u = *(const uint4*)&Vh[base + (size_t)(t0 + 2 * u) * 64 + sg * 8];
            r1.u = *(const uint4*)&Vh[base + (size_t)(t0 + 2 * u + 1) * 64 + sg * 8];
            #pragma unroll
            for (int e = 0; e < 8; e++) {
                uint32_t pk = (uint32_t)r0.s[e] | ((uint32_t)r1.s[e] << 16);
                *(uint32_t*)&Vt[(sg * 8 + e) * 72 + 2 * u] = pk;
            }
        }
        __syncthreads();

        // S^T = K Q^T : row=t=(qd*4+r), col=q=ln  (log2 domain)
        bf16x8 kb[4][2];
        #pragma unroll
        for (int tt = 0; tt < 4; tt++)
            #pragma unroll
            for (int ks = 0; ks < 2; ks++)
                kb[tt][ks] = *(const bf16x8*)&Ks[(tt * 16 + ln) * 72 + ks * 32 + qd * 8];
        f32x4 sa[4][2] = {};
        #pragma unroll
        for (int tt = 0; tt < 4; tt++)
            #pragma unroll
            for (int tq = 0; tq < 2; tq++)
                #pragma unroll
                for (int ks = 0; ks < 2; ks++)
                    sa[tt][tq] = __builtin_amdgcn_mfma_f32_16x16x32_bf16(kb[tt][ks], qf[tq][ks], sa[tt][tq], 0, 0, 0);

        // online softmax in log2 domain; state lives in lane ln (=q), quad-redundant
        float alpha[2];
        #pragma unroll
        for (int tq = 0; tq < 2; tq++) {
            float mx = -__builtin_inff();
            #pragma unroll
            for (int tt = 0; tt < 4; tt++)
                #pragma unroll
                for (int r = 0; r < 4; r++) mx = fmaxf(mx, sa[tt][tq][r]);
            mx = fmaxf(mx, __shfl_xor(mx, 16));
            mx = fmaxf(mx, __shfl_xor(mx, 32));
            float mnew = fmaxf(mrun[tq], mx);
            alpha[tq] = __builtin_amdgcn_exp2f(mrun[tq] - mnew);
            mrun[tq] = mnew;
            float rs = 0.f;
            #pragma unroll
            for (int tt = 0; tt < 4; tt++)
                #pragma unroll
                for (int r = 0; r < 4; r++) {
                    float p = __builtin_amdgcn_exp2f(sa[tt][tq][r] - mnew);
                    sa[tt][tq][r] = p; rs += p;
                }
            rs += __shfl_xor(rs, 16);
            rs += __shfl_xor(rs, 32);
            lrun[tq] = lrun[tq] * alpha[tq] + rs;
            // P^T -> Ps [q][t]: 4 consecutive t per lane, packed b64
            #pragma unroll
            for (int tt = 0; tt < 4; tt++) {
                uint2 pk;
                pk.x = pack_bf16_hu(sa[tt][tq][0], sa[tt][tq][1]);
                pk.y = pack_bf16_hu(sa[tt][tq][2], sa[tt][tq][3]);
                *(uint2*)&Ps[(w * 32 + tq * 16 + ln) * 72 + tt * 16 + qd * 4] = pk;
            }
            // O^T rescale: col=q=ln -> alpha already in the right lane, no shuffles
            #pragma unroll
            for (int dt = 0; dt < 4; dt++)
                #pragma unroll
                for (int r = 0; r < 4; r++) oacc[tq][dt][r] *= alpha[tq];
        }

        // O^T += V^T P^T  (A = V^T from Vt, B = P^T from Ps; Ps rows wave-private)
        bf16x8 pa[2][2], vb[4][2];
        #pragma unroll
        for (int tq = 0; tq < 2; tq++)
            #pragma unroll
            for (int ks = 0; ks < 2; ks++)
                pa[tq][ks] = *(const bf16x8*)&Ps[(w * 32 + tq * 16 + ln) * 72 + ks * 32 + qd * 8];
        #pragma unroll
        for (int dt = 0; dt < 4; dt++)
            #pragma unroll
            for (int ks = 0; ks < 2; ks++)
                vb[dt][ks] = *(const bf16x8*)&Vt[(dt * 16 + ln) * 72 + ks * 32 + qd * 8];
        #pragma unroll
        for (int tq = 0; tq < 2; tq++)
            #pragma unroll
            for (int dt = 0; dt < 4; dt++)
                #pragma unroll
                for (int ks = 0; ks < 2; ks++)
                    oacc[tq][dt] = __builtin_amdgcn_mfma_f32_16x16x32_bf16(vb[dt][ks], pa[tq][ks], oacc[tq][dt], 0, 0, 0);
    }

    // normalize (inv already in right lane), pack d-consecutive b64 into Ps, then store
    #pragma unroll
    for (int tq = 0; tq < 2; tq++) {
        float inv = 1.0f / lrun[tq];
        #pragma unroll
        for (int dt = 0; dt < 4; dt++) {
            uint2 pk;
            pk.x = pack_bf16_hu(oacc[tq][dt][0] * inv, oacc[tq][dt][1] * inv);
            pk.y = pack_bf16_hu(oacc[tq][dt][2] * inv, oacc[tq][dt][3] * inv);
            *(uint2*)&Ps[(w * 32 + tq * 16 + ln) * 72 + dt * 16 + qd * 4] = pk;
        }
    }
    __syncthreads();
    #pragma unroll
    for (int i = 0; i < 4; i++) {
        int c = tid + i * 512, row = c >> 3, sg = c & 7;
        *(uint4*)&Of[base + (size_t)(q0 + row) * 64 + sg * 8] =
            *(const uint4*)&Ps[row * 72 + sg * 8];
    }
}

// ---------- launch ----------
extern "C" void kernel_launch(void* const* d_in, const int* in_sizes, int n_in,
                              void* d_out, int out_size, void* d_ws, size_t ws_size,
                              hipStream_t stream) {
    const float* q   = (const float*)d_in[0];
    const float* k   = (const float*)d_in[1];
    const float* v   = (const float*)d_in[2];
    const float* w_q = (const float*)d_in[3];
    const float* b_q = (const float*)d_in[4];
    const float* w_k = (const float*)d_in[5];
    const float* b_k = (const float*)d_in[6];
    const float* w_v = (const float*)d_in[7];
    const float* b_v = (const float*)d_in[8];
    const float* w_0 = (const float*)d_in[9];
    const float* b_0 = (const float*)d_in[10];

    uint16_t* ws  = (uint16_t*)d_ws;
    const size_t WE = 1048576, NE = 8388608;
    uint16_t* wtq = ws;
    uint16_t* wtk = wtq + WE;
    uint16_t* wtv = wtk + WE;
    uint16_t* wt0 = wtv + WE;
    uint16_t* xq  = wt0 + WE;
    uint16_t* xk  = xq + NE;
    uint16_t* xv  = xk + NE;
    uint16_t* Qh  = xv + NE;
    uint16_t* Kh  = Qh + NE;
    uint16_t* Vh  = Kh + NE;
    uint16_t* Pf  = xq;              // alias: xq dead after QKV projection

    const dim3 tb(256);
    const dim3 gT(16, 16, 4);
    const dim3 gC(8192, 3);          // fused cast
    const dim3 gQ(8, 64, 3);         // fused QKV GEMM
    const dim3 gO(8, 64);            // output GEMM
    const dim3 gA(8, 64);            // attn: 256-row q tiles
    const int  n4 = 2097152;

    // Q scale folds 1/sqrt(dk) AND log2(e) for exp2-domain softmax
    const float qscale = 0.125f * 1.44269504f;

    transpose_cast4<<<gT, tb, 0, stream>>>(w_q, w_k, w_v, w_0, wtq, wtk, wtv, wt0);
    cast3_f32_bf16<<<gC, tb, 0, stream>>>(q, k, v, xq, xk, xv, n4);
    gemm_qkv<<<gQ, tb, 0, stream>>>(xq, xk, xv, wtq, wtk, wtv, b_q, b_k, b_v,
                                    Qh, Kh, Vh, qscale);
    attn_kernel<<<gA, dim3(512), 0, stream>>>(Qh, Kh, Vh, Pf);
    gemm_o<<<gO, tb, 0, stream>>>(Pf, wt0, b_0, (float*)d_out);
}